// Round 9
// baseline (288.440 us; speedup 1.0000x reference)
//
#include <hip/hip_runtime.h>
#include <hip/hip_bf16.h>

// PointProp for MI355X (gfx950) — R13.
//   kP: prep (Wc = W0r@Wu@Wm folded; bias chain)     kC: pack weights (bf16)
//   kF: WAVE-LOCAL 2-TILE PIPELINE, register-disciplined (R11 retry).
//       R11's spill cause: bulk sg[16] + ring + csa/csb peaked ~270 VGPR.
//       Fixes: (a) act DOUBLE-BUFFER in LDS (X=csum, Y=sig/act; 16KB/wave,
//       64KB/block, 2 blocks/CU) — sig rows go global->reg->Y 2 rows/phase
//       during passA, never bulk-held; (b) stream ring = ONE named 3-pair
//       bank (24 VGPR, lag-1); (c) prologue burst = two named 4-pair banks;
//       (d) every stream access uses literal pair indices (no dynamic
//       array indexing anywhere). Steady peak ~233 VGPR at (256,2).
//       Per wave: burst tile0 csum (chip 268MB, HBM-bound) -> tile0 MLP
//       while streaming tile1 csum (MLP hides under stream) -> tile1 MLP.
//       csum round-trip eliminated; no barriers; no cross-block sync.
// Math: out = L4(relu(L3(relu(L2(relu(sig@W0s^T + csum@Wc^T + bias1))))))
// with Wc = W0r@Wu@Wm folded (linearity), H padded 132->160.

typedef float  f32x4  __attribute__((ext_vector_type(4)));
typedef __bf16 bf16x8 __attribute__((ext_vector_type(8)));
typedef unsigned int   u32x2 __attribute__((ext_vector_type(2)));
typedef unsigned int   u32x4 __attribute__((ext_vector_type(4)));
typedef unsigned short u16x8 __attribute__((ext_vector_type(8)));

__device__ __forceinline__ unsigned short f2bf(float f) {
  unsigned int u = __builtin_bit_cast(unsigned int, f);
  u += 0x7fffu + ((u >> 16) & 1u);   // RNE
  return (unsigned short)(u >> 16);
}

__device__ __forceinline__ u32x2 pack4(f32x4 v) {
  u32x2 r;
  r[0] = (unsigned)f2bf(v[0]) | ((unsigned)f2bf(v[1]) << 16);
  r[1] = (unsigned)f2bf(v[2]) | ((unsigned)f2bf(v[3]) << 16);
  return r;
}

// ---------------- Kernel P: all prep (Wc, bias1, padded biases) -------------
__global__ __launch_bounds__(256) void kP(
    const float* __restrict__ W0, const float* __restrict__ Wu,
    const float* __restrict__ Wm, const float* __restrict__ bm,
    const float* __restrict__ bu, const float* __restrict__ b0,
    const float* __restrict__ b1, const float* __restrict__ b2,
    float* __restrict__ Wc, float* __restrict__ bias1,
    float* __restrict__ b1p, float* __restrict__ b2p) {
  const int b = blockIdx.x;
  const int d = threadIdx.x;
  if (b < 132) {
    __shared__ float u[256];
    const int h = b;
    float s = 0.f;
#pragma unroll 8
    for (int i = 0; i < 256; ++i) s += W0[h * 512 + 256 + i] * Wu[i * 256 + d];
    u[d] = s;
    __syncthreads();
    float s2 = 0.f;
#pragma unroll 8
    for (int j = 0; j < 256; ++j) s2 += u[j] * Wm[j * 256 + d];
    Wc[h * 256 + d] = s2;
  } else {
    __shared__ float bml[256];
    __shared__ float rbl[256];
    bml[d] = bm[d];
    __syncthreads();
    {
      const f32x4* wr = (const f32x4*)(Wu + d * 256);
      const f32x4* bm4 = (const f32x4*)bml;
      float s = 0.f;
#pragma unroll 8
      for (int i = 0; i < 64; ++i) {
        f32x4 w = wr[i], v = bm4[i];
        s += w[0] * v[0] + w[1] * v[1] + w[2] * v[2] + w[3] * v[3];
      }
      rbl[d] = 8.f * s + bu[d];
    }
    __syncthreads();
    if (d < 160) {
      float v = 0.f;
      if (d < 132) {
        float s = 0.f;
#pragma unroll 8
        for (int j = 0; j < 256; ++j) s += W0[d * 512 + 256 + j] * rbl[j];
        v = b0[d] + s;
      }
      bias1[d] = v;
      b1p[d] = (d < 132) ? b1[d] : 0.f;
      b2p[d] = (d < 132) ? b2[d] : 0.f;
    }
  }
}

// ---------------- Kernel C: pack weights to MFMA B-frag order (bf16) --------
// Chunk (kk,nt) = 1024B: lane l holds B[kk*32+(l>>4)*8+j][nt*16+(l&15)], j=0..7.
// L1: K=512,N=160; L2/L3: 160x160; L4: 160x256. Chunk c at c*10240 (c=0..25);
// L4 (kk,h) 8-frag group at 266240 + kk*16384 + h*8192.
__global__ __launch_bounds__(256) void kC(
    const float* __restrict__ W0, const float* __restrict__ Wc,
    const float* __restrict__ W1, const float* __restrict__ W2,
    const float* __restrict__ W3,
    unsigned short* __restrict__ P1, unsigned short* __restrict__ P2,
    unsigned short* __restrict__ P3, unsigned short* __restrict__ P4) {
  int e = blockIdx.x * 256 + threadIdx.x;
  if (e >= 174080) return;
  unsigned short* dst; int NT, rel, mode;
  if (e < 81920)       { dst = P1; NT = 10; rel = e;          mode = 0; }
  else if (e < 107520) { dst = P2; NT = 10; rel = e - 81920;  mode = 1; }
  else if (e < 133120) { dst = P3; NT = 10; rel = e - 107520; mode = 2; }
  else                 { dst = P4; NT = 16; rel = e - 133120; mode = 3; }
  int chunk = rel >> 9, q = rel & 511;
  int lane = q >> 3, j = q & 7;
  int kk = chunk / NT, nt = chunk - kk * NT;
  int k = kk * 32 + (lane >> 4) * 8 + j;
  int n = nt * 16 + (lane & 15);
  float v = 0.f;
  if (mode == 0) {
    if (n < 132) v = (k < 256) ? W0[n * 512 + k] : Wc[n * 256 + (k - 256)];
  } else if (mode == 1) {
    if (n < 132 && k < 132) v = W1[n * 132 + k];
  } else if (mode == 2) {
    if (n < 132 && k < 132) v = W2[n * 132 + k];
  } else {
    if (k < 132) v = W3[n * 132 + k];
  }
  dst[rel] = f2bf(v);
}

// ---- per-wave weight issue (direct L2/L1 -> VGPR, coalesced 1KB/frag) ----
#define WISS(BUF, CHUNK)                                                     \
  {                                                                          \
    _Pragma("unroll") for (int nt = 0; nt < 10; ++nt)                        \
        BUF[nt] = *(const bf16x8*)(Pb + (CHUNK) * 10240 + nt * 1024 +        \
                                   lane * 16);                               \
  }
#define WISS8L4(BUF, Q)                                                      \
  {                                                                          \
    _Pragma("unroll") for (int nt = 0; nt < 8; ++nt)                         \
        BUF[nt] = *(const bf16x8*)(Pb + 266240 + ((Q) % 5) * 16384 +         \
                                   ((Q) / 5) * 8192 + nt * 1024 + lane * 16);\
  }
#define MFMA10(ACC, BUF, AF)                                                 \
  {                                                                          \
    _Pragma("unroll") for (int nt = 0; nt < 10; ++nt)                        \
        ACC[nt] = __builtin_amdgcn_mfma_f32_16x16x32_bf16(AF, BUF[nt],       \
                                                          ACC[nt], 0, 0, 0); \
  }

// ---- stream macros (literal pair indices only; pair pi: k=pi&7, j=pi>>3,
//      rows row1+2j+r2, cols c32*8..+7; csa=lo half, csb=hi half) ----
#define CADDR(PI) \
  ((size_t)((PI) & 7) * 4194304u + nbase + (size_t)((PI) >> 3) * 128)
#define SISS3(P0, P1, P2)                                                    \
  { s0a = cp[CADDR(P0)]; s0b = cp[CADDR(P0) + 1];                            \
    s1a = cp[CADDR(P1)]; s1b = cp[CADDR(P1) + 1];                            \
    s2a = cp[CADDR(P2)]; s2b = cp[CADDR(P2) + 1]; }
#define SCON3(P0, P1, P2)                                                    \
  { csa[(P0) >> 3] += s0a; csb[(P0) >> 3] += s0b;                            \
    csa[(P1) >> 3] += s1a; csb[(P1) >> 3] += s1b;                            \
    csa[(P2) >> 3] += s2a; csb[(P2) >> 3] += s2b; }
#define SISS2(P0, P1)                                                        \
  { s0a = cp[CADDR(P0)]; s0b = cp[CADDR(P0) + 1];                            \
    s1a = cp[CADDR(P1)]; s1b = cp[CADDR(P1) + 1]; }
#define SCON2(P0, P1)                                                        \
  { csa[(P0) >> 3] += s0a; csb[(P0) >> 3] += s0b;                            \
    csa[(P1) >> 3] += s1a; csb[(P1) >> 3] += s1b; }

// ---- prologue burst (tile0): group G = (j=G>>1, k-half=G&1), 4 pairs ----
#define PADDR(G, I) \
  ((size_t)(((G) & 1) * 4 + (I)) * 4194304u + base0 + (size_t)((G) >> 1) * 128)
#define PISS(BK, G)                                                          \
  { BK##0a = cp[PADDR(G, 0)]; BK##0b = cp[PADDR(G, 0) + 1];                  \
    BK##1a = cp[PADDR(G, 1)]; BK##1b = cp[PADDR(G, 1) + 1];                  \
    BK##2a = cp[PADDR(G, 2)]; BK##2b = cp[PADDR(G, 2) + 1];                  \
    BK##3a = cp[PADDR(G, 3)]; BK##3b = cp[PADDR(G, 3) + 1]; }
#define PCON(BK, G)                                                          \
  { csa[(G) >> 1] += ((BK##0a + BK##1a) + (BK##2a + BK##3a));                \
    csb[(G) >> 1] += ((BK##0b + BK##1b) + (BK##2b + BK##3b)); }

// write csum accumulators -> X (bf16, swizzled) and reset
#define WCSX()                                                               \
  {                                                                          \
    asm volatile("" ::: "memory");                                           \
    _Pragma("unroll") for (int j = 0; j < 8; ++j) {                          \
      const int rw = 2 * j + r2;                                             \
      u32x2 lo = pack4(csa[j]), hi = pack4(csb[j]);                          \
      *(u32x4*)(X + rw * 512 + ((c32 * 16) ^ ((rw & 7) << 4))) =             \
          u32x4{lo[0], lo[1], hi[0], hi[1]};                                 \
    }                                                                        \
    asm volatile("" ::: "memory");                                           \
  }
#define ZCS()                                                                \
  {                                                                          \
    _Pragma("unroll") for (int j = 0; j < 8; ++j) {                          \
      csa[j] = f32x4{0.f, 0.f, 0.f, 0.f};                                    \
      csb[j] = f32x4{0.f, 0.f, 0.f, 0.f};                                    \
    }                                                                        \
  }
#define BIASRELU(BIASP)                                                      \
  {                                                                          \
    float bv[10];                                                            \
    _Pragma("unroll") for (int nt = 0; nt < 10; ++nt)                        \
        bv[nt] = (BIASP)[nt * 16 + l16];                                     \
    asm volatile("" ::: "memory");                                           \
    _Pragma("unroll") for (int nt = 0; nt < 10; ++nt) {                      \
      _Pragma("unroll") for (int r = 0; r < 4; ++r) {                        \
        const int row = lhalf * 4 + r;                                       \
        float v = fmaxf(acc[nt][r] + bv[nt], 0.f);                           \
        *(unsigned short*)(Y + row * 512 +                                   \
                           (((nt * 16 + l16) * 2) ^ ((row & 7) << 4))) =     \
            f2bf(v);                                                         \
      }                                                                      \
    }                                                                        \
    asm volatile("" ::: "memory");                                           \
  }
#define ZACC()                                                               \
  { _Pragma("unroll") for (int i = 0; i < 10; ++i)                           \
        acc[i] = f32x4{0.f, 0.f, 0.f, 0.f}; }

// ---------------- Kernel F: wave-local 2-tile pipelined comp-sum + MLP ------
// grid 512 x 256 (fully resident at 2 blocks/CU); wave owns rows
// [gid*32, gid*32+32) as tiles t0=[+0,+16), t1=[+16,+32). LDS 16KB/wave:
// X (csum act) + Y (sig/hidden act), both XOR-swizzled.
__global__ __launch_bounds__(256, 2) void kF(
    const float* __restrict__ signal, const float* __restrict__ comp,
    const unsigned short* __restrict__ Pseq,
    const float* __restrict__ bias1, const float* __restrict__ b1p,
    const float* __restrict__ b2p, const float* __restrict__ b3,
    float* __restrict__ out) {
  extern __shared__ char lds[];
  const int tid = threadIdx.x;
  const int wave = tid >> 6;
  const int lane = tid & 63;
  const int lhalf = lane >> 4;
  const int l16 = lane & 15;
  const int r2 = lane >> 5, c32 = lane & 31;
  char* X = lds + wave * 16384;
  char* Y = X + 8192;
  const char* Pb = (const char*)Pseq;
  const int gid = (int)blockIdx.x * 4 + wave;     // 0..2047
  const int row0 = gid * 32;
  const int row1 = row0 + 16;
  const int asw = (l16 & 7) << 4;
  const f32x4* sp = (const f32x4*)signal;
  const f32x4* cp = (const f32x4*)comp;
  const size_t base0 = (size_t)(row0 + r2) * 64 + c32 * 2;
  const size_t nbase = (size_t)(row1 + r2) * 64 + c32 * 2;

  bf16x8 wA[10], wB[10], w4A[8], w4B[8];
  f32x4 csa[8], csb[8], acc[10];
  f32x4 s0a, s0b, s1a, s1b, s2a, s2b;

  // ======== prologue: tile0 csum burst (two named 4-pair banks) ========
  WISS(wA, 8);                          // passA chunk 8 (long lead time)
  ZCS();
  {
    f32x4 tA0a, tA0b, tA1a, tA1b, tA2a, tA2b, tA3a, tA3b;
    f32x4 tB0a, tB0b, tB1a, tB1b, tB2a, tB2b, tB3a, tB3b;
    PISS(tA, 0); PISS(tB, 1);
#pragma unroll
    for (int gg = 0; gg < 7; ++gg) {
      PCON(tA, 2 * gg);     PISS(tA, 2 * gg + 2);
      PCON(tB, 2 * gg + 1); PISS(tB, 2 * gg + 3);
    }
    PCON(tA, 14); PCON(tB, 15);
  }
  WCSX();                               // tile0 csum -> X
  ZCS();                                // accumulators now for tile1

  // ================= TILE 0 (streams tile1 csum) =================
  ZACC();
  // passA: csum chunks 8..15 from X; sig rows -> Y (2/phase)
#pragma unroll
  for (int ph = 0; ph < 8; ++ph) {
    f32x4 g0 = sp[(size_t)(row0 + 2 * ph) * 64 + lane];
    f32x4 g1 = sp[(size_t)(row0 + 2 * ph + 1) * 64 + lane];
    *(u32x2*)(Y + (2 * ph) * 512 + ((lane * 8) ^ (((2 * ph) & 7) << 4))) =
        pack4(g0);
    *(u32x2*)(Y + (2 * ph + 1) * 512 +
              ((lane * 8) ^ (((2 * ph + 1) & 7) << 4))) = pack4(g1);
    const int cn = (ph < 7) ? (9 + ph) : 0;
    if ((cn & 1)) { WISS(wB, cn); } else { WISS(wA, cn); }
    bf16x8 af =
        *(const bf16x8*)(X + l16 * 512 + ((ph * 64 + lhalf * 16) ^ asw));
    if (ph & 1) { MFMA10(acc, wB, af); } else { MFMA10(acc, wA, af); }
  }
  // passB: sig chunks 0..7 from Y; stream f=0..7 (3 pairs/phase)
#pragma unroll
  for (int f = 0; f < 8; ++f) {
    if (f == 0) { SISS3(0, 1, 2); }
    else { SCON3(3 * f - 3, 3 * f - 2, 3 * f - 1);
           SISS3(3 * f, 3 * f + 1, 3 * f + 2); }
    const int cn = (f < 7) ? (f + 1) : 16;
    if ((cn & 1)) { WISS(wB, cn); } else { WISS(wA, cn); }
    bf16x8 af =
        *(const bf16x8*)(Y + l16 * 512 + ((f * 64 + lhalf * 16) ^ asw));
    if (f & 1) { MFMA10(acc, wB, af); } else { MFMA10(acc, wA, af); }
  }
  BIASRELU(bias1);
  // L2/L3: chunks 16..25; stream f=8..17 (2 pairs/phase)
#pragma unroll
  for (int L = 0; L < 2; ++L) {
    ZACC();
#pragma unroll
    for (int q = 0; q < 5; ++q) {
      const int cc = 16 + L * 5 + q;
      const int f = 8 + L * 5 + q;
      if (f == 8) { SCON3(21, 22, 23); }
      else { SCON2(24 + 2 * (f - 9), 25 + 2 * (f - 9)); }
      SISS2(24 + 2 * (f - 8), 25 + 2 * (f - 8));
      if (cc < 25) {
        if (((cc + 1) & 1)) { WISS(wB, cc + 1); } else { WISS(wA, cc + 1); }
      } else {
        WISS8L4(w4A, 0);
      }
      bf16x8 af =
          *(const bf16x8*)(Y + l16 * 512 + ((q * 64 + lhalf * 16) ^ asw));
      if (cc & 1) { MFMA10(acc, wB, af); } else { MFMA10(acc, wA, af); }
    }
    if (L) { BIASRELU(b2p); } else { BIASRELU(b1p); }
  }
  // L4: halves H=0,1 x kk=0..4; stream f=18..27 (2 pairs/phase)
#pragma unroll
  for (int H = 0; H < 2; ++H) {
    f32x4 a4[8];
#pragma unroll
    for (int i = 0; i < 8; ++i) a4[i] = f32x4{0.f, 0.f, 0.f, 0.f};
#pragma unroll
    for (int kk = 0; kk < 5; ++kk) {
      const int q = H * 5 + kk;
      const int f = 18 + q;
      SCON2(24 + 2 * (f - 9), 25 + 2 * (f - 9));
      if (f < 27) { SISS2(24 + 2 * (f - 8), 25 + 2 * (f - 8)); }
      else { SISS2(62, 63); }
      if (q < 9) {
        if (q & 1) { WISS8L4(w4A, q + 1); } else { WISS8L4(w4B, q + 1); }
      } else {
        WISS(wA, 8);                      // tile1 passA chunk 8
      }
      bf16x8 af =
          *(const bf16x8*)(Y + l16 * 512 + ((kk * 64 + lhalf * 16) ^ asw));
#pragma unroll
      for (int i = 0; i < 8; ++i) {
        if (q & 1)
          a4[i] = __builtin_amdgcn_mfma_f32_16x16x32_bf16(af, w4B[i], a4[i],
                                                          0, 0, 0);
        else
          a4[i] = __builtin_amdgcn_mfma_f32_16x16x32_bf16(af, w4A[i], a4[i],
                                                          0, 0, 0);
      }
    }
    float bv[8];
#pragma unroll
    for (int i = 0; i < 8; ++i) bv[i] = b3[(H * 8 + i) * 16 + l16];
    float* op = out + (size_t)(row0 + lhalf * 4) * 256 + H * 128 + l16;
#pragma unroll
    for (int i = 0; i < 8; ++i) {
#pragma unroll
      for (int r = 0; r < 4; ++r)
        op[(size_t)r * 256 + i * 16] = a4[i][r] + bv[i];
    }
  }
  SCON2(62, 63);                          // drain

  // ================= TILE 1 (no stream) =================
  WCSX();                                 // tile1 csum -> X
  ZACC();
#pragma unroll
  for (int ph = 0; ph < 8; ++ph) {
    f32x4 g0 = sp[(size_t)(row1 + 2 * ph) * 64 + lane];
    f32x4 g1 = sp[(size_t)(row1 + 2 * ph + 1) * 64 + lane];
    *(u32x2*)(Y + (2 * ph) * 512 + ((lane * 8) ^ (((2 * ph) & 7) << 4))) =
        pack4(g0);
    *(u32x2*)(Y + (2 * ph + 1) * 512 +
              ((lane * 8) ^ (((2 * ph + 1) & 7) << 4))) = pack4(g1);
    const int cn = (ph < 7) ? (9 + ph) : 0;
    if ((cn & 1)) { WISS(wB, cn); } else { WISS(wA, cn); }
    bf16x8 af =
        *(const bf16x8*)(X + l16 * 512 + ((ph * 64 + lhalf * 16) ^ asw));
    if (ph & 1) { MFMA10(acc, wB, af); } else { MFMA10(acc, wA, af); }
  }
#pragma unroll
  for (int f = 0; f < 8; ++f) {
    const int cn = (f < 7) ? (f + 1) : 16;
    if ((cn & 1)) { WISS(wB, cn); } else { WISS(wA, cn); }
    bf16x8 af =
        *(const bf16x8*)(Y + l16 * 512 + ((f * 64 + lhalf * 16) ^ asw));
    if (f & 1) { MFMA10(acc, wB, af); } else { MFMA10(acc, wA, af); }
  }
  BIASRELU(bias1);
#pragma unroll
  for (int L = 0; L < 2; ++L) {
    ZACC();
#pragma unroll
    for (int q = 0; q < 5; ++q) {
      const int cc = 16 + L * 5 + q;
      if (cc < 25) {
        if (((cc + 1) & 1)) { WISS(wB, cc + 1); } else { WISS(wA, cc + 1); }
      } else {
        WISS8L4(w4A, 0);
      }
      bf16x8 af =
          *(const bf16x8*)(Y + l16 * 512 + ((q * 64 + lhalf * 16) ^ asw));
      if (cc & 1) { MFMA10(acc, wB, af); } else { MFMA10(acc, wA, af); }
    }
    if (L) { BIASRELU(b2p); } else { BIASRELU(b1p); }
  }
#pragma unroll
  for (int H = 0; H < 2; ++H) {
    f32x4 a4[8];
#pragma unroll
    for (int i = 0; i < 8; ++i) a4[i] = f32x4{0.f, 0.f, 0.f, 0.f};
#pragma unroll
    for (int kk = 0; kk < 5; ++kk) {
      const int q = H * 5 + kk;
      if (q < 9) {
        if (q & 1) { WISS8L4(w4A, q + 1); } else { WISS8L4(w4B, q + 1); }
      }
      bf16x8 af =
          *(const bf16x8*)(Y + l16 * 512 + ((kk * 64 + lhalf * 16) ^ asw));
#pragma unroll
      for (int i = 0; i < 8; ++i) {
        if (q & 1)
          a4[i] = __builtin_amdgcn_mfma_f32_16x16x32_bf16(af, w4B[i], a4[i],
                                                          0, 0, 0);
        else
          a4[i] = __builtin_amdgcn_mfma_f32_16x16x32_bf16(af, w4A[i], a4[i],
                                                          0, 0, 0);
      }
    }
    float bv[8];
#pragma unroll
    for (int i = 0; i < 8; ++i) bv[i] = b3[(H * 8 + i) * 16 + l16];
    float* op = out + (size_t)(row1 + lhalf * 4) * 256 + H * 128 + l16;
#pragma unroll
    for (int i = 0; i < 8; ++i) {
#pragma unroll
      for (int r = 0; r < 4; ++r)
        op[(size_t)r * 256 + i * 16] = a4[i][r] + bv[i];
    }
  }
}

// ---------------- launcher ----------------
extern "C" void kernel_launch(void* const* d_in, const int* in_sizes, int n_in,
                              void* d_out, int out_size, void* d_ws, size_t ws_size,
                              hipStream_t stream) {
  const float* signal = (const float*)d_in[0];
  const float* comp   = (const float*)d_in[1];
  const float* Wm = (const float*)d_in[2];
  const float* bm = (const float*)d_in[3];
  const float* Wu = (const float*)d_in[4];
  const float* bu = (const float*)d_in[5];
  const float* W0 = (const float*)d_in[6];
  const float* b0 = (const float*)d_in[7];
  const float* W1 = (const float*)d_in[8];
  const float* b1 = (const float*)d_in[9];
  const float* W2 = (const float*)d_in[10];
  const float* b2 = (const float*)d_in[11];
  const float* W3 = (const float*)d_in[12];
  const float* b3 = (const float*)d_in[13];

  char* ws = (char*)d_ws;
  float* Wc    = (float*)(ws + 0);        // 33792 f32 (135168 B)
  float* bias1 = (float*)(ws + 135168);   // 160 f32
  float* b1p   = (float*)(ws + 135808);   // 160 f32
  float* b2p   = (float*)(ws + 136448);   // 160 f32
  unsigned short* P1 = (unsigned short*)(ws + 137216);  // 81920 u16 (160KB)
  unsigned short* P2 = (unsigned short*)(ws + 301056);  // 25600 u16 (50KB)
  unsigned short* P3 = (unsigned short*)(ws + 352256);  // 25600 u16 (50KB)
  unsigned short* P4 = (unsigned short*)(ws + 403456);  // 40960 u16 (80KB)

  hipLaunchKernelGGL(kP, dim3(133), dim3(256), 0, stream,
                     W0, Wu, Wm, bm, bu, b0, b1, b2, Wc, bias1, b1p, b2p);
  hipLaunchKernelGGL(kC, dim3(680), dim3(256), 0, stream,
                     W0, Wc, W1, W2, W3, P1, P2, P3, P4);
  hipLaunchKernelGGL(kF, dim3(512), dim3(256), 65536, stream,
                     signal, comp, P1, bias1, b1p, b2p, b3, (float*)d_out);
}

// Round 10
// 186.913 us; speedup vs baseline: 1.5432x; 1.5432x over previous
//
#include <hip/hip_runtime.h>
#include <hip/hip_bf16.h>

// PointProp for MI355X (gfx950) — R14 (= R10, the verified best at 187.2us).
//   kA: prep1 + comp-sum (k-serial, pure stream -> ~6.3 TB/s, ~91us)
//   kB: prep2   kC: pack weights to MFMA frag order
//   kD: 4-layer MLP, 32 rows/wave (two 16-row groups), B-frags in REGISTERS
//       shared by both groups, wave-private act tiles, no barriers.
// Session ledger (why this structure): R5-R9, R11, R13 all tried to overlap
// the 537MB comp stream with the csum-dependent MLP and all lost:
//   - agent-scope flags (R8): XCD L2 non-coherence -> 4x slower than serial
//   - co-resident lockstep fusion (R6/R7): stream compressed into pass-1
//   - direct A-frag loads (R9): lane=row -> uncoalesced (64x 16B txns)
//   - wave-local 2-tile pipeline (R11/R13): mixing streaming loads with
//     latency-critical weight loads in one wave -> conservative vmcnt
//     placement collapses stream depth to ~2-3 TB/s (+ VGPR spills at >256).
// Lesson: keep the pure stream (kA) separate from the latency-sensitive
// MLP (kD). Remaining slack is inside kD (~88us vs ~40us resource floor);
// its bottleneck is not identifiable from available counters (poison fills
// crowd the dispatch table), so locking in the verified best.
// Math: out = L4(relu(L3(relu(L2(relu(sig@W0s^T + csum@Wc^T + bias1))))))
// with Wc = W0r@Wu@Wm folded (linearity), H padded 132->160.

typedef float  f32x4  __attribute__((ext_vector_type(4)));
typedef __bf16 bf16x8 __attribute__((ext_vector_type(8)));
typedef unsigned int   u32x2 __attribute__((ext_vector_type(2)));
typedef unsigned short u16x8 __attribute__((ext_vector_type(8)));

__device__ __forceinline__ unsigned short f2bf(float f) {
  unsigned int u = __builtin_bit_cast(unsigned int, f);
  u += 0x7fffu + ((u >> 16) & 1u);   // RNE
  return (unsigned short)(u >> 16);
}

__device__ __forceinline__ u32x2 pack4(f32x4 v) {
  u32x2 r;
  r[0] = (unsigned)f2bf(v[0]) | ((unsigned)f2bf(v[1]) << 16);
  r[1] = (unsigned)f2bf(v[2]) | ((unsigned)f2bf(v[3]) << 16);
  return r;
}

__device__ __forceinline__ float wave_reduce(float s) {
#pragma unroll
  for (int m = 32; m > 0; m >>= 1) s += __shfl_xor(s, m, 64);
  return s;
}

// ---------------- Kernel A: prep1 (U, rb) + comp-sum (k-serial) -------------
// blocks 0..131: U = W0r@Wu ; 132..195: rb = 8*(Wu@bm)+bu
// blocks 196..2243: block cb owns rows [cb*32, cb*32+32); k-serial.
__global__ __launch_bounds__(256) void kA(const float* __restrict__ comp,
                                          const float* __restrict__ W0,
                                          const float* __restrict__ Wu,
                                          const float* __restrict__ bm,
                                          const float* __restrict__ bu,
                                          float* __restrict__ U,
                                          float* __restrict__ rb,
                                          unsigned short* __restrict__ csum) {
  const int b = blockIdx.x;
  if (b >= 196) {
    const int cb = b - 196;                       // 0..2047
    const int t = threadIdx.x;
    const f32x4* cp = (const f32x4*)comp;
    const size_t base = (size_t)cb * 2048 + t;    // f32x4 units
    f32x4 a[8];
#pragma unroll
    for (int j = 0; j < 8; ++j) a[j] = cp[base + j * 256];
#pragma unroll
    for (int k = 1; k < 8; ++k) {
      f32x4 t0[8];
#pragma unroll
      for (int j = 0; j < 8; ++j) t0[j] = cp[base + (size_t)k * 4194304u + j * 256];
#pragma unroll
      for (int j = 0; j < 8; ++j) a[j] += t0[j];
    }
    u32x2* op = (u32x2*)csum;
#pragma unroll
    for (int j = 0; j < 8; ++j) op[base + j * 256] = pack4(a[j]);
  } else if (b < 132) {
    const int h = b, d = threadIdx.x;
    float s = 0.f;
#pragma unroll 8
    for (int i = 0; i < 256; ++i) s += W0[h * 512 + 256 + i] * Wu[i * 256 + d];
    U[h * 256 + d] = s;
  } else {
    const int t = (b - 132) * 4 + (threadIdx.x >> 6);   // 0..255
    const int lane = threadIdx.x & 63;
    f32x4 w = ((const f32x4*)(Wu + t * 256))[lane];
    f32x4 v = ((const f32x4*)bm)[lane];
    float s = w[0] * v[0] + w[1] * v[1] + w[2] * v[2] + w[3] * v[3];
    s = wave_reduce(s);
    if (lane == 0) rb[t] = 8.f * s + bu[t];
  }
}

// ---------------- Kernel B: prep2 (Wc, bias1, padded biases) ----------------
__global__ __launch_bounds__(256) void kB(const float* __restrict__ U,
                                          const float* __restrict__ Wm,
                                          const float* __restrict__ W0,
                                          const float* __restrict__ rb,
                                          const float* __restrict__ b0,
                                          const float* __restrict__ b1,
                                          const float* __restrict__ b2,
                                          float* __restrict__ Wc,
                                          float* __restrict__ bias1,
                                          float* __restrict__ b1p,
                                          float* __restrict__ b2p) {
  const int b = blockIdx.x;
  if (b < 132) {
    const int h = b, d = threadIdx.x;
    float s = 0.f;
#pragma unroll 8
    for (int j = 0; j < 256; ++j) s += U[h * 256 + j] * Wm[j * 256 + d];
    Wc[h * 256 + d] = s;
  } else {
    const int t = (b - 132) * 4 + (threadIdx.x >> 6);   // 0..159
    const int lane = threadIdx.x & 63;
    float v = 0.f;
    if (t < 132) {
      f32x4 w = ((const f32x4*)(W0 + t * 512 + 256))[lane];
      f32x4 r4 = ((const f32x4*)rb)[lane];
      float s = w[0] * r4[0] + w[1] * r4[1] + w[2] * r4[2] + w[3] * r4[3];
      s = wave_reduce(s);
      v = b0[t] + s;
    }
    if (lane == 0) {
      bias1[t] = v;
      b1p[t] = (t < 132) ? b1[t] : 0.f;
      b2p[t] = (t < 132) ? b2[t] : 0.f;
    }
  }
}

// ---------------- Kernel C: pack weights to MFMA B-frag order (bf16) --------
// Chunk (kk,nt) = 1024B: lane l holds B[kk*32+(l>>4)*8+j][nt*16+(l&15)], j=0..7.
// L1: K=512,N=160; L2/L3: 160x160; L4: 160x256. P1..P4 CONTIGUOUS in ws.
__global__ __launch_bounds__(256) void kC(
    const float* __restrict__ W0, const float* __restrict__ Wc,
    const float* __restrict__ W1, const float* __restrict__ W2,
    const float* __restrict__ W3,
    unsigned short* __restrict__ P1, unsigned short* __restrict__ P2,
    unsigned short* __restrict__ P3, unsigned short* __restrict__ P4) {
  int e = blockIdx.x * 256 + threadIdx.x;
  if (e >= 174080) return;
  unsigned short* dst; int NT, rel, mode;
  if (e < 81920)       { dst = P1; NT = 10; rel = e;          mode = 0; }
  else if (e < 107520) { dst = P2; NT = 10; rel = e - 81920;  mode = 1; }
  else if (e < 133120) { dst = P3; NT = 10; rel = e - 107520; mode = 2; }
  else                 { dst = P4; NT = 16; rel = e - 133120; mode = 3; }
  int chunk = rel >> 9, q = rel & 511;
  int lane = q >> 3, j = q & 7;
  int kk = chunk / NT, nt = chunk - kk * NT;
  int k = kk * 32 + (lane >> 4) * 8 + j;
  int n = nt * 16 + (lane & 15);
  float v = 0.f;
  if (mode == 0) {
    if (n < 132) v = (k < 256) ? W0[n * 512 + k] : Wc[n * 256 + (k - 256)];
  } else if (mode == 1) {
    if (n < 132 && k < 132) v = W1[n * 132 + k];
  } else if (mode == 2) {
    if (n < 132 && k < 132) v = W2[n * 132 + k];
  } else {
    if (k < 132) v = W3[n * 132 + k];
  }
  dst[rel] = f2bf(v);
}

// ---- per-wave weight issue (direct L2/L1 -> VGPR, coalesced 1KB per frag) --
// chunks 0..25 contiguous at c*10240; L4 chunk (h,kk) 8-frag group at
// 266240 + kk*16384 + h*8192.
#define WISS(BUF, CHUNK)                                                     \
  {                                                                          \
    _Pragma("unroll") for (int nt = 0; nt < 10; ++nt)                        \
        BUF[nt] = *(const bf16x8*)(Pb + (CHUNK) * 10240 + nt * 1024 +        \
                                   lane * 16);                               \
  }
#define WISS8L4(BUF, Q)                                                      \
  {                                                                          \
    _Pragma("unroll") for (int nt = 0; nt < 8; ++nt)                         \
        BUF[nt] = *(const bf16x8*)(Pb + 266240 + ((Q) % 5) * 16384 +         \
                                   ((Q) / 5) * 8192 + nt * 1024 + lane * 16);\
  }
#define MFMA10(ACC, BUF, AF)                                                 \
  {                                                                          \
    _Pragma("unroll") for (int nt = 0; nt < 10; ++nt)                        \
        ACC[nt] = __builtin_amdgcn_mfma_f32_16x16x32_bf16(AF, BUF[nt],       \
                                                          ACC[nt], 0, 0, 0); \
  }

// ---------------- Kernel D: 4-layer MLP, 32 rows/wave, register weights -----
// grid 512 x 256; wave owns 32 rows as two 16-row groups (act0/act1, 8KB
// each, wave-private, XOR-swizzled). One WISS feeds both groups' MFMAs.
__global__ __launch_bounds__(256, 2) void kD(
    const float* __restrict__ signal, const unsigned short* __restrict__ csum,
    const unsigned short* __restrict__ Pseq,
    const float* __restrict__ bias1, const float* __restrict__ b1p,
    const float* __restrict__ b2p, const float* __restrict__ b3,
    float* __restrict__ out) {
  extern __shared__ char lds[];
  const int tid = threadIdx.x;
  const int wave = tid >> 6;
  const int lane = tid & 63;
  const int lhalf = lane >> 4;
  const int l16 = lane & 15;
  const int r2 = lane >> 5, c32 = lane & 31;
  char* act0 = lds + wave * 16384;
  char* act1 = act0 + 8192;
  const char* Pb = (const char*)Pseq;
  const int row0 = ((int)blockIdx.x * 4 + wave) * 32;
  const int asw = (l16 & 7) << 4;
  const f32x4* sp = (const f32x4*)signal;

  // ---- prologue: signal -> act tiles (one group at a time: caps VGPRs) ----
  {
    f32x4 sg[16];
#pragma unroll
    for (int r = 0; r < 16; ++r) sg[r] = sp[(size_t)(row0 + r) * 64 + lane];
#pragma unroll
    for (int r = 0; r < 16; ++r)
      *(u32x2*)(act0 + r * 512 + ((lane * 8) ^ ((r & 7) << 4))) = pack4(sg[r]);
  }
  {
    f32x4 sg[16];
#pragma unroll
    for (int r = 0; r < 16; ++r)
      sg[r] = sp[(size_t)(row0 + 16 + r) * 64 + lane];
#pragma unroll
    for (int r = 0; r < 16; ++r)
      *(u32x2*)(act1 + r * 512 + ((lane * 8) ^ ((r & 7) << 4))) = pack4(sg[r]);
  }

  // csum for both groups (issued early; consumed at pass-2 switch)
  u16x8 cs0[8], cs1[8];
#pragma unroll
  for (int j = 0; j < 8; ++j)
    cs0[j] = *(const u16x8*)(csum + (size_t)(row0 + 2 * j + r2) * 256 + c32 * 8);
#pragma unroll
  for (int j = 0; j < 8; ++j)
    cs1[j] =
        *(const u16x8*)(csum + (size_t)(row0 + 16 + 2 * j + r2) * 256 + c32 * 8);

  bf16x8 wA[10], wB[10];
  WISS(wA, 0);

  f32x4 acc0[10], acc1[10];
#pragma unroll
  for (int i = 0; i < 10; ++i) {
    acc0[i] = f32x4{0.f, 0.f, 0.f, 0.f};
    acc1[i] = f32x4{0.f, 0.f, 0.f, 0.f};
  }

  // ---- L1 pass 1 (signal half), chunks 0..7 ----
#pragma unroll
  for (int kk = 0; kk < 8; ++kk) {
    if ((kk + 1) & 1) { WISS(wB, kk + 1); } else { WISS(wA, kk + 1); }
    bf16x8 af0 =
        *(const bf16x8*)(act0 + l16 * 512 + ((kk * 64 + lhalf * 16) ^ asw));
    bf16x8 af1 =
        *(const bf16x8*)(act1 + l16 * 512 + ((kk * 64 + lhalf * 16) ^ asw));
    if (kk & 1) {
      MFMA10(acc0, wB, af0); MFMA10(acc1, wB, af1);
    } else {
      MFMA10(acc0, wA, af0); MFMA10(acc1, wA, af1);
    }
  }

  // overwrite act tiles with comp-sum (wave-local)
  asm volatile("" ::: "memory");
#pragma unroll
  for (int j = 0; j < 8; ++j) {
    const int rw = 2 * j + r2;
    *(u16x8*)(act0 + rw * 512 + ((c32 * 16) ^ ((rw & 7) << 4))) = cs0[j];
    *(u16x8*)(act1 + rw * 512 + ((c32 * 16) ^ ((rw & 7) << 4))) = cs1[j];
  }
  asm volatile("" ::: "memory");

  // ---- L1 pass 2 (comp-sum half), chunks 8..15 ----
#pragma unroll
  for (int kk = 8; kk < 16; ++kk) {
    if ((kk + 1) & 1) { WISS(wB, kk + 1); } else { WISS(wA, kk + 1); }
    bf16x8 af0 = *(const bf16x8*)(act0 + l16 * 512 +
                                  (((kk - 8) * 64 + lhalf * 16) ^ asw));
    bf16x8 af1 = *(const bf16x8*)(act1 + l16 * 512 +
                                  (((kk - 8) * 64 + lhalf * 16) ^ asw));
    if (kk & 1) {
      MFMA10(acc0, wB, af0); MFMA10(acc1, wB, af1);
    } else {
      MFMA10(acc0, wA, af0); MFMA10(acc1, wA, af1);
    }
  }

  // bias + relu -> act tiles
  {
    float bv[10];
#pragma unroll
    for (int nt = 0; nt < 10; ++nt) bv[nt] = bias1[nt * 16 + l16];
    asm volatile("" ::: "memory");
#pragma unroll
    for (int nt = 0; nt < 10; ++nt) {
#pragma unroll
      for (int r = 0; r < 4; ++r) {
        const int row = lhalf * 4 + r;
        const int off = (((nt * 16 + l16) * 2) ^ ((row & 7) << 4));
        float v0 = fmaxf(acc0[nt][r] + bv[nt], 0.f);
        float v1 = fmaxf(acc1[nt][r] + bv[nt], 0.f);
        *(unsigned short*)(act0 + row * 512 + off) = f2bf(v0);
        *(unsigned short*)(act1 + row * 512 + off) = f2bf(v1);
      }
    }
    asm volatile("" ::: "memory");
  }

  // ---- hidden layers: chunks 16..20 (W1), 21..25 (W2) ----
  bf16x8 w4A[8], w4B[8];
#pragma unroll
  for (int L = 0; L < 2; ++L) {
    const float* hbias = L ? b2p : b1p;
#pragma unroll
    for (int i = 0; i < 10; ++i) {
      acc0[i] = f32x4{0.f, 0.f, 0.f, 0.f};
      acc1[i] = f32x4{0.f, 0.f, 0.f, 0.f};
    }
#pragma unroll
    for (int qq = 0; qq < 5; ++qq) {
      const int cc = 16 + L * 5 + qq;      // chunk in use (even->wA, odd->wB)
      if (cc < 25) {
        if (cc & 1) { WISS(wA, cc + 1); } else { WISS(wB, cc + 1); }
      } else {
        WISS8L4(w4A, 0);                   // prefetch L4 q=0
      }
      bf16x8 af0 =
          *(const bf16x8*)(act0 + l16 * 512 + ((qq * 64 + lhalf * 16) ^ asw));
      bf16x8 af1 =
          *(const bf16x8*)(act1 + l16 * 512 + ((qq * 64 + lhalf * 16) ^ asw));
      if (cc & 1) {
        MFMA10(acc0, wB, af0); MFMA10(acc1, wB, af1);
      } else {
        MFMA10(acc0, wA, af0); MFMA10(acc1, wA, af1);
      }
    }
    float bv[10];
#pragma unroll
    for (int nt = 0; nt < 10; ++nt) bv[nt] = hbias[nt * 16 + l16];
    asm volatile("" ::: "memory");
#pragma unroll
    for (int nt = 0; nt < 10; ++nt) {
#pragma unroll
      for (int r = 0; r < 4; ++r) {
        const int row = lhalf * 4 + r;
        const int off = (((nt * 16 + l16) * 2) ^ ((row & 7) << 4));
        float v0 = fmaxf(acc0[nt][r] + bv[nt], 0.f);
        float v1 = fmaxf(acc1[nt][r] + bv[nt], 0.f);
        *(unsigned short*)(act0 + row * 512 + off) = f2bf(v0);
        *(unsigned short*)(act1 + row * 512 + off) = f2bf(v1);
      }
    }
    asm volatile("" ::: "memory");
  }

  // ---- layer 4: two N-128 halves h=0,1; q = h*5+kk (even->w4A, odd->w4B) --
#pragma unroll
  for (int h = 0; h < 2; ++h) {
    f32x4 a40[8], a41[8];
#pragma unroll
    for (int i = 0; i < 8; ++i) {
      a40[i] = f32x4{0.f, 0.f, 0.f, 0.f};
      a41[i] = f32x4{0.f, 0.f, 0.f, 0.f};
    }
#pragma unroll
    for (int kk = 0; kk < 5; ++kk) {
      const int q = h * 5 + kk;
      if (q < 9) {
        if (q & 1) { WISS8L4(w4A, q + 1); } else { WISS8L4(w4B, q + 1); }
      }
      bf16x8 af0 =
          *(const bf16x8*)(act0 + l16 * 512 + ((kk * 64 + lhalf * 16) ^ asw));
      bf16x8 af1 =
          *(const bf16x8*)(act1 + l16 * 512 + ((kk * 64 + lhalf * 16) ^ asw));
#pragma unroll
      for (int i = 0; i < 8; ++i) {
        if (q & 1) {
          a40[i] = __builtin_amdgcn_mfma_f32_16x16x32_bf16(af0, w4B[i], a40[i],
                                                           0, 0, 0);
          a41[i] = __builtin_amdgcn_mfma_f32_16x16x32_bf16(af1, w4B[i], a41[i],
                                                           0, 0, 0);
        } else {
          a40[i] = __builtin_amdgcn_mfma_f32_16x16x32_bf16(af0, w4A[i], a40[i],
                                                           0, 0, 0);
          a41[i] = __builtin_amdgcn_mfma_f32_16x16x32_bf16(af1, w4A[i], a41[i],
                                                           0, 0, 0);
        }
      }
    }
    // store this half for both groups
    float bv[8];
#pragma unroll
    for (int i = 0; i < 8; ++i) bv[i] = b3[(h * 8 + i) * 16 + l16];
    float* op0 = out + (size_t)(row0 + lhalf * 4) * 256 + h * 128 + l16;
    float* op1 = out + (size_t)(row0 + 16 + lhalf * 4) * 256 + h * 128 + l16;
#pragma unroll
    for (int i = 0; i < 8; ++i) {
#pragma unroll
      for (int r = 0; r < 4; ++r) {
        op0[(size_t)r * 256 + i * 16] = a40[i][r] + bv[i];
        op1[(size_t)r * 256 + i * 16] = a41[i][r] + bv[i];
      }
    }
  }
}

// ---------------- launcher ----------------
extern "C" void kernel_launch(void* const* d_in, const int* in_sizes, int n_in,
                              void* d_out, int out_size, void* d_ws, size_t ws_size,
                              hipStream_t stream) {
  const float* signal = (const float*)d_in[0];
  const float* comp   = (const float*)d_in[1];
  const float* Wm = (const float*)d_in[2];
  const float* bm = (const float*)d_in[3];
  const float* Wu = (const float*)d_in[4];
  const float* bu = (const float*)d_in[5];
  const float* W0 = (const float*)d_in[6];
  const float* b0 = (const float*)d_in[7];
  const float* W1 = (const float*)d_in[8];
  const float* b1 = (const float*)d_in[9];
  const float* W2 = (const float*)d_in[10];
  const float* b2 = (const float*)d_in[11];
  const float* W3 = (const float*)d_in[12];
  const float* b3 = (const float*)d_in[13];

  char* ws = (char*)d_ws;
  float* U     = (float*)(ws + 0);        // 33792 f32
  float* Wc    = (float*)(ws + 135168);   // 33792 f32
  float* bias1 = (float*)(ws + 270336);   // 160 f32
  float* b1p   = (float*)(ws + 270976);   // 160 f32
  float* b2p   = (float*)(ws + 271616);   // 160 f32
  float* rb    = (float*)(ws + 272256);   // 256 f32
  // contiguous packed-weight sequence (stage chunks index off P1):
  unsigned short* P1 = (unsigned short*)(ws + 273408);  // 81920 u16 (160KB)
  unsigned short* P2 = (unsigned short*)(ws + 437248);  // 25600 u16 (50KB)
  unsigned short* P3 = (unsigned short*)(ws + 488448);  // 25600 u16 (50KB)
  unsigned short* P4 = (unsigned short*)(ws + 539648);  // 40960 u16 (80KB)
  unsigned short* csum = (unsigned short*)(ws + 621568); // [N,256] bf16, 33.5MB

  hipLaunchKernelGGL(kA, dim3(2244), dim3(256), 0, stream,
                     comp, W0, Wu, bm, bu, U, rb, csum);
  hipLaunchKernelGGL(kB, dim3(172), dim3(256), 0, stream,
                     U, Wm, W0, rb, b0, b1, b2, Wc, bias1, b1p, b2p);
  hipLaunchKernelGGL(kC, dim3(680), dim3(256), 0, stream,
                     W0, Wc, W1, W2, W3, P1, P2, P3, P4);
  hipLaunchKernelGGL(kD, dim3(512), dim3(256), 65536, stream,
                     signal, csum, P1, bias1, b1p, b2p, b3, (float*)d_out);
}

// Round 11
// 180.285 us; speedup vs baseline: 1.5999x; 1.0368x over previous
//
#include <hip/hip_runtime.h>
#include <hip/hip_bf16.h>

// PointProp for MI355X (gfx950) — R15 (= R14/R10 + s_setprio on kD's MFMA
// clusters).
//   kA: prep1 + comp-sum (k-serial, pure stream -> ~6.3 TB/s, ~91us; at its
//       HBM roofline)
//   kB: prep2   kC: pack weights to MFMA frag order
//   kD: 4-layer MLP, 32 rows/wave (two 16-row groups), B-frags in REGISTERS
//       shared by both groups, wave-private act tiles, no barriers.
//       NEW: __builtin_amdgcn_s_setprio(1) around each 20-MFMA cluster.
//       Rationale: kD's waves are independent (no barriers) and alternate
//       {L2 weight burst}/{MFMA cluster}; setprio helps exactly this regime
//       (independent waves at different phases — attn analog, +4-7%) while
//       being null only for barrier-lockstep waves.
// Session ledger: all stream/MLP overlap structures lost (XCD-non-coherent
// flags 4x; lockstep fusion compresses stream; direct A-frags uncoalesced;
// wave-local stream+latency mix collapses vmcnt depth; >256 live VGPR
// spills). Serial best: 186.9us.
// Math: out = L4(relu(L3(relu(L2(relu(sig@W0s^T + csum@Wc^T + bias1))))))
// with Wc = W0r@Wu@Wm folded (linearity), H padded 132->160.

typedef float  f32x4  __attribute__((ext_vector_type(4)));
typedef __bf16 bf16x8 __attribute__((ext_vector_type(8)));
typedef unsigned int   u32x2 __attribute__((ext_vector_type(2)));
typedef unsigned short u16x8 __attribute__((ext_vector_type(8)));

__device__ __forceinline__ unsigned short f2bf(float f) {
  unsigned int u = __builtin_bit_cast(unsigned int, f);
  u += 0x7fffu + ((u >> 16) & 1u);   // RNE
  return (unsigned short)(u >> 16);
}

__device__ __forceinline__ u32x2 pack4(f32x4 v) {
  u32x2 r;
  r[0] = (unsigned)f2bf(v[0]) | ((unsigned)f2bf(v[1]) << 16);
  r[1] = (unsigned)f2bf(v[2]) | ((unsigned)f2bf(v[3]) << 16);
  return r;
}

__device__ __forceinline__ float wave_reduce(float s) {
#pragma unroll
  for (int m = 32; m > 0; m >>= 1) s += __shfl_xor(s, m, 64);
  return s;
}

// ---------------- Kernel A: prep1 (U, rb) + comp-sum (k-serial) -------------
// blocks 0..131: U = W0r@Wu ; 132..195: rb = 8*(Wu@bm)+bu
// blocks 196..2243: block cb owns rows [cb*32, cb*32+32); k-serial.
__global__ __launch_bounds__(256) void kA(const float* __restrict__ comp,
                                          const float* __restrict__ W0,
                                          const float* __restrict__ Wu,
                                          const float* __restrict__ bm,
                                          const float* __restrict__ bu,
                                          float* __restrict__ U,
                                          float* __restrict__ rb,
                                          unsigned short* __restrict__ csum) {
  const int b = blockIdx.x;
  if (b >= 196) {
    const int cb = b - 196;                       // 0..2047
    const int t = threadIdx.x;
    const f32x4* cp = (const f32x4*)comp;
    const size_t base = (size_t)cb * 2048 + t;    // f32x4 units
    f32x4 a[8];
#pragma unroll
    for (int j = 0; j < 8; ++j) a[j] = cp[base + j * 256];
#pragma unroll
    for (int k = 1; k < 8; ++k) {
      f32x4 t0[8];
#pragma unroll
      for (int j = 0; j < 8; ++j) t0[j] = cp[base + (size_t)k * 4194304u + j * 256];
#pragma unroll
      for (int j = 0; j < 8; ++j) a[j] += t0[j];
    }
    u32x2* op = (u32x2*)csum;
#pragma unroll
    for (int j = 0; j < 8; ++j) op[base + j * 256] = pack4(a[j]);
  } else if (b < 132) {
    const int h = b, d = threadIdx.x;
    float s = 0.f;
#pragma unroll 8
    for (int i = 0; i < 256; ++i) s += W0[h * 512 + 256 + i] * Wu[i * 256 + d];
    U[h * 256 + d] = s;
  } else {
    const int t = (b - 132) * 4 + (threadIdx.x >> 6);   // 0..255
    const int lane = threadIdx.x & 63;
    f32x4 w = ((const f32x4*)(Wu + t * 256))[lane];
    f32x4 v = ((const f32x4*)bm)[lane];
    float s = w[0] * v[0] + w[1] * v[1] + w[2] * v[2] + w[3] * v[3];
    s = wave_reduce(s);
    if (lane == 0) rb[t] = 8.f * s + bu[t];
  }
}

// ---------------- Kernel B: prep2 (Wc, bias1, padded biases) ----------------
__global__ __launch_bounds__(256) void kB(const float* __restrict__ U,
                                          const float* __restrict__ Wm,
                                          const float* __restrict__ W0,
                                          const float* __restrict__ rb,
                                          const float* __restrict__ b0,
                                          const float* __restrict__ b1,
                                          const float* __restrict__ b2,
                                          float* __restrict__ Wc,
                                          float* __restrict__ bias1,
                                          float* __restrict__ b1p,
                                          float* __restrict__ b2p) {
  const int b = blockIdx.x;
  if (b < 132) {
    const int h = b, d = threadIdx.x;
    float s = 0.f;
#pragma unroll 8
    for (int j = 0; j < 256; ++j) s += U[h * 256 + j] * Wm[j * 256 + d];
    Wc[h * 256 + d] = s;
  } else {
    const int t = (b - 132) * 4 + (threadIdx.x >> 6);   // 0..159
    const int lane = threadIdx.x & 63;
    float v = 0.f;
    if (t < 132) {
      f32x4 w = ((const f32x4*)(W0 + t * 512 + 256))[lane];
      f32x4 r4 = ((const f32x4*)rb)[lane];
      float s = w[0] * r4[0] + w[1] * r4[1] + w[2] * r4[2] + w[3] * r4[3];
      s = wave_reduce(s);
      v = b0[t] + s;
    }
    if (lane == 0) {
      bias1[t] = v;
      b1p[t] = (t < 132) ? b1[t] : 0.f;
      b2p[t] = (t < 132) ? b2[t] : 0.f;
    }
  }
}

// ---------------- Kernel C: pack weights to MFMA B-frag order (bf16) --------
// Chunk (kk,nt) = 1024B: lane l holds B[kk*32+(l>>4)*8+j][nt*16+(l&15)], j=0..7.
// L1: K=512,N=160; L2/L3: 160x160; L4: 160x256. P1..P4 CONTIGUOUS in ws.
__global__ __launch_bounds__(256) void kC(
    const float* __restrict__ W0, const float* __restrict__ Wc,
    const float* __restrict__ W1, const float* __restrict__ W2,
    const float* __restrict__ W3,
    unsigned short* __restrict__ P1, unsigned short* __restrict__ P2,
    unsigned short* __restrict__ P3, unsigned short* __restrict__ P4) {
  int e = blockIdx.x * 256 + threadIdx.x;
  if (e >= 174080) return;
  unsigned short* dst; int NT, rel, mode;
  if (e < 81920)       { dst = P1; NT = 10; rel = e;          mode = 0; }
  else if (e < 107520) { dst = P2; NT = 10; rel = e - 81920;  mode = 1; }
  else if (e < 133120) { dst = P3; NT = 10; rel = e - 107520; mode = 2; }
  else                 { dst = P4; NT = 16; rel = e - 133120; mode = 3; }
  int chunk = rel >> 9, q = rel & 511;
  int lane = q >> 3, j = q & 7;
  int kk = chunk / NT, nt = chunk - kk * NT;
  int k = kk * 32 + (lane >> 4) * 8 + j;
  int n = nt * 16 + (lane & 15);
  float v = 0.f;
  if (mode == 0) {
    if (n < 132) v = (k < 256) ? W0[n * 512 + k] : Wc[n * 256 + (k - 256)];
  } else if (mode == 1) {
    if (n < 132 && k < 132) v = W1[n * 132 + k];
  } else if (mode == 2) {
    if (n < 132 && k < 132) v = W2[n * 132 + k];
  } else {
    if (k < 132) v = W3[n * 132 + k];
  }
  dst[rel] = f2bf(v);
}

// ---- per-wave weight issue (direct L2/L1 -> VGPR, coalesced 1KB per frag) --
// chunks 0..25 contiguous at c*10240; L4 chunk (h,kk) 8-frag group at
// 266240 + kk*16384 + h*8192.
#define WISS(BUF, CHUNK)                                                     \
  {                                                                          \
    _Pragma("unroll") for (int nt = 0; nt < 10; ++nt)                        \
        BUF[nt] = *(const bf16x8*)(Pb + (CHUNK) * 10240 + nt * 1024 +        \
                                   lane * 16);                               \
  }
#define WISS8L4(BUF, Q)                                                      \
  {                                                                          \
    _Pragma("unroll") for (int nt = 0; nt < 8; ++nt)                         \
        BUF[nt] = *(const bf16x8*)(Pb + 266240 + ((Q) % 5) * 16384 +         \
                                   ((Q) / 5) * 8192 + nt * 1024 + lane * 16);\
  }
#define MFMA10(ACC, BUF, AF)                                                 \
  {                                                                          \
    _Pragma("unroll") for (int nt = 0; nt < 10; ++nt)                        \
        ACC[nt] = __builtin_amdgcn_mfma_f32_16x16x32_bf16(AF, BUF[nt],       \
                                                          ACC[nt], 0, 0, 0); \
  }

// ---------------- Kernel D: 4-layer MLP, 32 rows/wave, register weights -----
// grid 512 x 256; wave owns 32 rows as two 16-row groups (act0/act1, 8KB
// each, wave-private, XOR-swizzled). One WISS feeds both groups' MFMAs.
// s_setprio(1) around each MFMA cluster: waves are independent (no barriers),
// so a compute-phase wave preempts load-issue-phase waves on the SIMD.
__global__ __launch_bounds__(256, 2) void kD(
    const float* __restrict__ signal, const unsigned short* __restrict__ csum,
    const unsigned short* __restrict__ Pseq,
    const float* __restrict__ bias1, const float* __restrict__ b1p,
    const float* __restrict__ b2p, const float* __restrict__ b3,
    float* __restrict__ out) {
  extern __shared__ char lds[];
  const int tid = threadIdx.x;
  const int wave = tid >> 6;
  const int lane = tid & 63;
  const int lhalf = lane >> 4;
  const int l16 = lane & 15;
  const int r2 = lane >> 5, c32 = lane & 31;
  char* act0 = lds + wave * 16384;
  char* act1 = act0 + 8192;
  const char* Pb = (const char*)Pseq;
  const int row0 = ((int)blockIdx.x * 4 + wave) * 32;
  const int asw = (l16 & 7) << 4;
  const f32x4* sp = (const f32x4*)signal;

  // ---- prologue: signal -> act tiles (one group at a time: caps VGPRs) ----
  {
    f32x4 sg[16];
#pragma unroll
    for (int r = 0; r < 16; ++r) sg[r] = sp[(size_t)(row0 + r) * 64 + lane];
#pragma unroll
    for (int r = 0; r < 16; ++r)
      *(u32x2*)(act0 + r * 512 + ((lane * 8) ^ ((r & 7) << 4))) = pack4(sg[r]);
  }
  {
    f32x4 sg[16];
#pragma unroll
    for (int r = 0; r < 16; ++r)
      sg[r] = sp[(size_t)(row0 + 16 + r) * 64 + lane];
#pragma unroll
    for (int r = 0; r < 16; ++r)
      *(u32x2*)(act1 + r * 512 + ((lane * 8) ^ ((r & 7) << 4))) = pack4(sg[r]);
  }

  // csum for both groups (issued early; consumed at pass-2 switch)
  u16x8 cs0[8], cs1[8];
#pragma unroll
  for (int j = 0; j < 8; ++j)
    cs0[j] = *(const u16x8*)(csum + (size_t)(row0 + 2 * j + r2) * 256 + c32 * 8);
#pragma unroll
  for (int j = 0; j < 8; ++j)
    cs1[j] =
        *(const u16x8*)(csum + (size_t)(row0 + 16 + 2 * j + r2) * 256 + c32 * 8);

  bf16x8 wA[10], wB[10];
  WISS(wA, 0);

  f32x4 acc0[10], acc1[10];
#pragma unroll
  for (int i = 0; i < 10; ++i) {
    acc0[i] = f32x4{0.f, 0.f, 0.f, 0.f};
    acc1[i] = f32x4{0.f, 0.f, 0.f, 0.f};
  }

  // ---- L1 pass 1 (signal half), chunks 0..7 ----
#pragma unroll
  for (int kk = 0; kk < 8; ++kk) {
    if ((kk + 1) & 1) { WISS(wB, kk + 1); } else { WISS(wA, kk + 1); }
    bf16x8 af0 =
        *(const bf16x8*)(act0 + l16 * 512 + ((kk * 64 + lhalf * 16) ^ asw));
    bf16x8 af1 =
        *(const bf16x8*)(act1 + l16 * 512 + ((kk * 64 + lhalf * 16) ^ asw));
    __builtin_amdgcn_s_setprio(1);
    if (kk & 1) {
      MFMA10(acc0, wB, af0); MFMA10(acc1, wB, af1);
    } else {
      MFMA10(acc0, wA, af0); MFMA10(acc1, wA, af1);
    }
    __builtin_amdgcn_s_setprio(0);
  }

  // overwrite act tiles with comp-sum (wave-local)
  asm volatile("" ::: "memory");
#pragma unroll
  for (int j = 0; j < 8; ++j) {
    const int rw = 2 * j + r2;
    *(u16x8*)(act0 + rw * 512 + ((c32 * 16) ^ ((rw & 7) << 4))) = cs0[j];
    *(u16x8*)(act1 + rw * 512 + ((c32 * 16) ^ ((rw & 7) << 4))) = cs1[j];
  }
  asm volatile("" ::: "memory");

  // ---- L1 pass 2 (comp-sum half), chunks 8..15 ----
#pragma unroll
  for (int kk = 8; kk < 16; ++kk) {
    if ((kk + 1) & 1) { WISS(wB, kk + 1); } else { WISS(wA, kk + 1); }
    bf16x8 af0 = *(const bf16x8*)(act0 + l16 * 512 +
                                  (((kk - 8) * 64 + lhalf * 16) ^ asw));
    bf16x8 af1 = *(const bf16x8*)(act1 + l16 * 512 +
                                  (((kk - 8) * 64 + lhalf * 16) ^ asw));
    __builtin_amdgcn_s_setprio(1);
    if (kk & 1) {
      MFMA10(acc0, wB, af0); MFMA10(acc1, wB, af1);
    } else {
      MFMA10(acc0, wA, af0); MFMA10(acc1, wA, af1);
    }
    __builtin_amdgcn_s_setprio(0);
  }

  // bias + relu -> act tiles
  {
    float bv[10];
#pragma unroll
    for (int nt = 0; nt < 10; ++nt) bv[nt] = bias1[nt * 16 + l16];
    asm volatile("" ::: "memory");
#pragma unroll
    for (int nt = 0; nt < 10; ++nt) {
#pragma unroll
      for (int r = 0; r < 4; ++r) {
        const int row = lhalf * 4 + r;
        const int off = (((nt * 16 + l16) * 2) ^ ((row & 7) << 4));
        float v0 = fmaxf(acc0[nt][r] + bv[nt], 0.f);
        float v1 = fmaxf(acc1[nt][r] + bv[nt], 0.f);
        *(unsigned short*)(act0 + row * 512 + off) = f2bf(v0);
        *(unsigned short*)(act1 + row * 512 + off) = f2bf(v1);
      }
    }
    asm volatile("" ::: "memory");
  }

  // ---- hidden layers: chunks 16..20 (W1), 21..25 (W2) ----
  bf16x8 w4A[8], w4B[8];
#pragma unroll
  for (int L = 0; L < 2; ++L) {
    const float* hbias = L ? b2p : b1p;
#pragma unroll
    for (int i = 0; i < 10; ++i) {
      acc0[i] = f32x4{0.f, 0.f, 0.f, 0.f};
      acc1[i] = f32x4{0.f, 0.f, 0.f, 0.f};
    }
#pragma unroll
    for (int qq = 0; qq < 5; ++qq) {
      const int cc = 16 + L * 5 + qq;      // chunk in use (even->wA, odd->wB)
      if (cc < 25) {
        if (cc & 1) { WISS(wA, cc + 1); } else { WISS(wB, cc + 1); }
      } else {
        WISS8L4(w4A, 0);                   // prefetch L4 q=0
      }
      bf16x8 af0 =
          *(const bf16x8*)(act0 + l16 * 512 + ((qq * 64 + lhalf * 16) ^ asw));
      bf16x8 af1 =
          *(const bf16x8*)(act1 + l16 * 512 + ((qq * 64 + lhalf * 16) ^ asw));
      __builtin_amdgcn_s_setprio(1);
      if (cc & 1) {
        MFMA10(acc0, wB, af0); MFMA10(acc1, wB, af1);
      } else {
        MFMA10(acc0, wA, af0); MFMA10(acc1, wA, af1);
      }
      __builtin_amdgcn_s_setprio(0);
    }
    float bv[10];
#pragma unroll
    for (int nt = 0; nt < 10; ++nt) bv[nt] = hbias[nt * 16 + l16];
    asm volatile("" ::: "memory");
#pragma unroll
    for (int nt = 0; nt < 10; ++nt) {
#pragma unroll
      for (int r = 0; r < 4; ++r) {
        const int row = lhalf * 4 + r;
        const int off = (((nt * 16 + l16) * 2) ^ ((row & 7) << 4));
        float v0 = fmaxf(acc0[nt][r] + bv[nt], 0.f);
        float v1 = fmaxf(acc1[nt][r] + bv[nt], 0.f);
        *(unsigned short*)(act0 + row * 512 + off) = f2bf(v0);
        *(unsigned short*)(act1 + row * 512 + off) = f2bf(v1);
      }
    }
    asm volatile("" ::: "memory");
  }

  // ---- layer 4: two N-128 halves h=0,1; q = h*5+kk (even->w4A, odd->w4B) --
#pragma unroll
  for (int h = 0; h < 2; ++h) {
    f32x4 a40[8], a41[8];
#pragma unroll
    for (int i = 0; i < 8; ++i) {
      a40[i] = f32x4{0.f, 0.f, 0.f, 0.f};
      a41[i] = f32x4{0.f, 0.f, 0.f, 0.f};
    }
#pragma unroll
    for (int kk = 0; kk < 5; ++kk) {
      const int q = h * 5 + kk;
      if (q < 9) {
        if (q & 1) { WISS8L4(w4A, q + 1); } else { WISS8L4(w4B, q + 1); }
      }
      bf16x8 af0 =
          *(const bf16x8*)(act0 + l16 * 512 + ((kk * 64 + lhalf * 16) ^ asw));
      bf16x8 af1 =
          *(const bf16x8*)(act1 + l16 * 512 + ((kk * 64 + lhalf * 16) ^ asw));
      __builtin_amdgcn_s_setprio(1);
#pragma unroll
      for (int i = 0; i < 8; ++i) {
        if (q & 1) {
          a40[i] = __builtin_amdgcn_mfma_f32_16x16x32_bf16(af0, w4B[i], a40[i],
                                                           0, 0, 0);
          a41[i] = __builtin_amdgcn_mfma_f32_16x16x32_bf16(af1, w4B[i], a41[i],
                                                           0, 0, 0);
        } else {
          a40[i] = __builtin_amdgcn_mfma_f32_16x16x32_bf16(af0, w4A[i], a40[i],
                                                           0, 0, 0);
          a41[i] = __builtin_amdgcn_mfma_f32_16x16x32_bf16(af1, w4A[i], a41[i],
                                                           0, 0, 0);
        }
      }
      __builtin_amdgcn_s_setprio(0);
    }
    // store this half for both groups
    float bv[8];
#pragma unroll
    for (int i = 0; i < 8; ++i) bv[i] = b3[(h * 8 + i) * 16 + l16];
    float* op0 = out + (size_t)(row0 + lhalf * 4) * 256 + h * 128 + l16;
    float* op1 = out + (size_t)(row0 + 16 + lhalf * 4) * 256 + h * 128 + l16;
#pragma unroll
    for (int i = 0; i < 8; ++i) {
#pragma unroll
      for (int r = 0; r < 4; ++r) {
        op0[(size_t)r * 256 + i * 16] = a40[i][r] + bv[i];
        op1[(size_t)r * 256 + i * 16] = a41[i][r] + bv[i];
      }
    }
  }
}

// ---------------- launcher ----------------
extern "C" void kernel_launch(void* const* d_in, const int* in_sizes, int n_in,
                              void* d_out, int out_size, void* d_ws, size_t ws_size,
                              hipStream_t stream) {
  const float* signal = (const float*)d_in[0];
  const float* comp   = (const float*)d_in[1];
  const float* Wm = (const float*)d_in[2];
  const float* bm = (const float*)d_in[3];
  const float* Wu = (const float*)d_in[4];
  const float* bu = (const float*)d_in[5];
  const float* W0 = (const float*)d_in[6];
  const float* b0 = (const float*)d_in[7];
  const float* W1 = (const float*)d_in[8];
  const float* b1 = (const float*)d_in[9];
  const float* W2 = (const float*)d_in[10];
  const float* b2 = (const float*)d_in[11];
  const float* W3 = (const float*)d_in[12];
  const float* b3 = (const float*)d_in[13];

  char* ws = (char*)d_ws;
  float* U     = (float*)(ws + 0);        // 33792 f32
  float* Wc    = (float*)(ws + 135168);   // 33792 f32
  float* bias1 = (float*)(ws + 270336);   // 160 f32
  float* b1p   = (float*)(ws + 270976);   // 160 f32
  float* b2p   = (float*)(ws + 271616);   // 160 f32
  float* rb    = (float*)(ws + 272256);   // 256 f32
  // contiguous packed-weight sequence (stage chunks index off P1):
  unsigned short* P1 = (unsigned short*)(ws + 273408);  // 81920 u16 (160KB)
  unsigned short* P2 = (unsigned short*)(ws + 437248);  // 25600 u16 (50KB)
  unsigned short* P3 = (unsigned short*)(ws + 488448);  // 25600 u16 (50KB)
  unsigned short* P4 = (unsigned short*)(ws + 539648);  // 40960 u16 (80KB)
  unsigned short* csum = (unsigned short*)(ws + 621568); // [N,256] bf16, 33.5MB

  hipLaunchKernelGGL(kA, dim3(2244), dim3(256), 0, stream,
                     comp, W0, Wu, bm, bu, U, rb, csum);
  hipLaunchKernelGGL(kB, dim3(172), dim3(256), 0, stream,
                     U, Wm, W0, rb, b0, b1, b2, Wc, bias1, b1p, b2p);
  hipLaunchKernelGGL(kC, dim3(680), dim3(256), 0, stream,
                     W0, Wc, W1, W2, W3, P1, P2, P3, P4);
  hipLaunchKernelGGL(kD, dim3(512), dim3(256), 65536, stream,
                     signal, csum, P1, bias1, b1p, b2p, b3, (float*)d_out);
}

// Round 12
// 174.985 us; speedup vs baseline: 1.6484x; 1.0303x over previous
//
#include <hip/hip_runtime.h>
#include <hip/hip_bf16.h>

// PointProp for MI355X (gfx950) — R16 (= R15 + prep-chain fusion).
//   kA: comp-sum (blocks 0..2047, streams first) + U->Wc per-block LDS chain
//       (blocks 2048..2179, kP-verified) + rb/bias1/b1p/b2p single block
//       (2180, kP-verified) + P2/P3/P4 packing (2181..2540, no deps).
//   kC: P1 packing only (needs Wc) — 320 blocks.
//   kD: R15 verbatim — 32 rows/wave, register B-frags shared by two 16-row
//       groups, wave-private act tiles, no barriers, s_setprio(1) around
//       MFMA clusters (the verified -6.6us win).
// Session ledger: overlap structures all lose (XCD-non-coherent flags 4x;
// lockstep fusion compresses the stream; direct A-frags uncoalesced;
// stream+latency mix in one wave collapses vmcnt depth; >256 live VGPR
// spills). Serial best: 180.3us (R15). This round only removes prep
// launches/time; kA and kD hot loops untouched.
// Math: out = L4(relu(L3(relu(L2(relu(sig@W0s^T + csum@Wc^T + bias1))))))
// with Wc = W0r@Wu@Wm folded (linearity), H padded 132->160.

typedef float  f32x4  __attribute__((ext_vector_type(4)));
typedef __bf16 bf16x8 __attribute__((ext_vector_type(8)));
typedef unsigned int   u32x2 __attribute__((ext_vector_type(2)));
typedef unsigned short u16x8 __attribute__((ext_vector_type(8)));

__device__ __forceinline__ unsigned short f2bf(float f) {
  unsigned int u = __builtin_bit_cast(unsigned int, f);
  u += 0x7fffu + ((u >> 16) & 1u);   // RNE
  return (unsigned short)(u >> 16);
}

__device__ __forceinline__ u32x2 pack4(f32x4 v) {
  u32x2 r;
  r[0] = (unsigned)f2bf(v[0]) | ((unsigned)f2bf(v[1]) << 16);
  r[1] = (unsigned)f2bf(v[2]) | ((unsigned)f2bf(v[3]) << 16);
  return r;
}

// ---------------- Kernel A: comp-sum + all non-P1 prep ----------------------
// blocks 0..2047: comp-sum rows [b*32, b*32+32), k-serial (pure HBM stream)
// blocks 2048..2179: h=b-2048: U row h (LDS) -> Wc row h   [kP pattern]
// block 2180: rb = 8*(Wu@bm)+bu; bias1 = b0 + W0r@rb; b1p/b2p [kP pattern]
// blocks 2181..2540: pack P2/P3/P4 (W1/W2/W3 only — independent)
__global__ __launch_bounds__(256) void kA(
    const float* __restrict__ comp, const float* __restrict__ W0,
    const float* __restrict__ Wu, const float* __restrict__ Wm,
    const float* __restrict__ bm, const float* __restrict__ bu,
    const float* __restrict__ b0, const float* __restrict__ b1,
    const float* __restrict__ b2, const float* __restrict__ W1,
    const float* __restrict__ W2, const float* __restrict__ W3,
    float* __restrict__ Wc, float* __restrict__ bias1,
    float* __restrict__ b1p, float* __restrict__ b2p,
    unsigned short* __restrict__ csum, unsigned short* __restrict__ P2,
    unsigned short* __restrict__ P3, unsigned short* __restrict__ P4) {
  const int b = blockIdx.x;
  const int d = threadIdx.x;
  if (b < 2048) {
    // ---- comp-sum (R15-kA verbatim; cb = b) ----
    const f32x4* cp = (const f32x4*)comp;
    const size_t base = (size_t)b * 2048 + d;     // f32x4 units
    f32x4 a[8];
#pragma unroll
    for (int j = 0; j < 8; ++j) a[j] = cp[base + j * 256];
#pragma unroll
    for (int k = 1; k < 8; ++k) {
      f32x4 t0[8];
#pragma unroll
      for (int j = 0; j < 8; ++j)
        t0[j] = cp[base + (size_t)k * 4194304u + j * 256];
#pragma unroll
      for (int j = 0; j < 8; ++j) a[j] += t0[j];
    }
    u32x2* op = (u32x2*)csum;
#pragma unroll
    for (int j = 0; j < 8; ++j) op[base + j * 256] = pack4(a[j]);
  } else if (b < 2180) {
    // ---- U row -> Wc row, chained through LDS (kP pattern) ----
    __shared__ float u[256];
    const int h = b - 2048;
    float s = 0.f;
#pragma unroll 8
    for (int i = 0; i < 256; ++i) s += W0[h * 512 + 256 + i] * Wu[i * 256 + d];
    u[d] = s;
    __syncthreads();
    float s2 = 0.f;
#pragma unroll 8
    for (int j = 0; j < 256; ++j) s2 += u[j] * Wm[j * 256 + d];
    Wc[h * 256 + d] = s2;
  } else if (b == 2180) {
    // ---- rb + bias1 + padded biases (kP block-132 pattern) ----
    __shared__ float bml[256];
    __shared__ float rbl[256];
    bml[d] = bm[d];
    __syncthreads();
    {
      const f32x4* wr = (const f32x4*)(Wu + d * 256);
      const f32x4* bm4 = (const f32x4*)bml;
      float s = 0.f;
#pragma unroll 8
      for (int i = 0; i < 64; ++i) {
        f32x4 w = wr[i], v = bm4[i];
        s += w[0] * v[0] + w[1] * v[1] + w[2] * v[2] + w[3] * v[3];
      }
      rbl[d] = 8.f * s + bu[d];
    }
    __syncthreads();
    if (d < 160) {
      float v = 0.f;
      if (d < 132) {
        float s = 0.f;
#pragma unroll 8
        for (int j = 0; j < 256; ++j) s += W0[d * 512 + 256 + j] * rbl[j];
        v = b0[d] + s;
      }
      bias1[d] = v;
      b1p[d] = (d < 132) ? b1[d] : 0.f;
      b2p[d] = (d < 132) ? b2[d] : 0.f;
    }
  } else {
    // ---- pack P2/P3/P4 (kC mode 1/2/3 verbatim; e2 = original e - 81920) --
    const int e2 = (b - 2181) * 256 + d;          // 0..92159
    unsigned short* dst; int NT, rel, mode;
    if (e2 < 25600)      { dst = P2; NT = 10; rel = e2;          mode = 1; }
    else if (e2 < 51200) { dst = P3; NT = 10; rel = e2 - 25600;  mode = 2; }
    else                 { dst = P4; NT = 16; rel = e2 - 51200;  mode = 3; }
    int chunk = rel >> 9, q = rel & 511;
    int lane = q >> 3, j = q & 7;
    int kk = chunk / NT, nt = chunk - kk * NT;
    int k = kk * 32 + (lane >> 4) * 8 + j;
    int n = nt * 16 + (lane & 15);
    float v = 0.f;
    if (mode == 1) {
      if (n < 132 && k < 132) v = W1[n * 132 + k];
    } else if (mode == 2) {
      if (n < 132 && k < 132) v = W2[n * 132 + k];
    } else {
      if (k < 132) v = W3[n * 132 + k];
    }
    dst[rel] = f2bf(v);
  }
}

// ---------------- Kernel C: pack P1 (needs Wc) ------------------------------
// Chunk (kk,nt) = 1024B: lane l holds B[kk*32+(l>>4)*8+j][nt*16+(l&15)], j=0..7.
// L1: K=512, N=160 -> 81920 elems, 320 blocks.
__global__ __launch_bounds__(256) void kC(
    const float* __restrict__ W0, const float* __restrict__ Wc,
    unsigned short* __restrict__ P1) {
  int e = blockIdx.x * 256 + threadIdx.x;        // 0..81919
  int chunk = e >> 9, q = e & 511;
  int lane = q >> 3, j = q & 7;
  int kk = chunk / 10, nt = chunk - kk * 10;
  int k = kk * 32 + (lane >> 4) * 8 + j;
  int n = nt * 16 + (lane & 15);
  float v = 0.f;
  if (n < 132) v = (k < 256) ? W0[n * 512 + k] : Wc[n * 256 + (k - 256)];
  P1[e] = f2bf(v);
}

// ---- per-wave weight issue (direct L2/L1 -> VGPR, coalesced 1KB per frag) --
// chunks 0..25 contiguous at c*10240; L4 chunk (h,kk) 8-frag group at
// 266240 + kk*16384 + h*8192.
#define WISS(BUF, CHUNK)                                                     \
  {                                                                          \
    _Pragma("unroll") for (int nt = 0; nt < 10; ++nt)                        \
        BUF[nt] = *(const bf16x8*)(Pb + (CHUNK) * 10240 + nt * 1024 +        \
                                   lane * 16);                               \
  }
#define WISS8L4(BUF, Q)                                                      \
  {                                                                          \
    _Pragma("unroll") for (int nt = 0; nt < 8; ++nt)                         \
        BUF[nt] = *(const bf16x8*)(Pb + 266240 + ((Q) % 5) * 16384 +         \
                                   ((Q) / 5) * 8192 + nt * 1024 + lane * 16);\
  }
#define MFMA10(ACC, BUF, AF)                                                 \
  {                                                                          \
    _Pragma("unroll") for (int nt = 0; nt < 10; ++nt)                        \
        ACC[nt] = __builtin_amdgcn_mfma_f32_16x16x32_bf16(AF, BUF[nt],       \
                                                          ACC[nt], 0, 0, 0); \
  }

// ---------------- Kernel D: 4-layer MLP (R15 verbatim, setprio win) ---------
__global__ __launch_bounds__(256, 2) void kD(
    const float* __restrict__ signal, const unsigned short* __restrict__ csum,
    const unsigned short* __restrict__ Pseq,
    const float* __restrict__ bias1, const float* __restrict__ b1p,
    const float* __restrict__ b2p, const float* __restrict__ b3,
    float* __restrict__ out) {
  extern __shared__ char lds[];
  const int tid = threadIdx.x;
  const int wave = tid >> 6;
  const int lane = tid & 63;
  const int lhalf = lane >> 4;
  const int l16 = lane & 15;
  const int r2 = lane >> 5, c32 = lane & 31;
  char* act0 = lds + wave * 16384;
  char* act1 = act0 + 8192;
  const char* Pb = (const char*)Pseq;
  const int row0 = ((int)blockIdx.x * 4 + wave) * 32;
  const int asw = (l16 & 7) << 4;
  const f32x4* sp = (const f32x4*)signal;

  // ---- prologue: signal -> act tiles (one group at a time: caps VGPRs) ----
  {
    f32x4 sg[16];
#pragma unroll
    for (int r = 0; r < 16; ++r) sg[r] = sp[(size_t)(row0 + r) * 64 + lane];
#pragma unroll
    for (int r = 0; r < 16; ++r)
      *(u32x2*)(act0 + r * 512 + ((lane * 8) ^ ((r & 7) << 4))) = pack4(sg[r]);
  }
  {
    f32x4 sg[16];
#pragma unroll
    for (int r = 0; r < 16; ++r)
      sg[r] = sp[(size_t)(row0 + 16 + r) * 64 + lane];
#pragma unroll
    for (int r = 0; r < 16; ++r)
      *(u32x2*)(act1 + r * 512 + ((lane * 8) ^ ((r & 7) << 4))) = pack4(sg[r]);
  }

  // csum for both groups (issued early; consumed at pass-2 switch)
  u16x8 cs0[8], cs1[8];
#pragma unroll
  for (int j = 0; j < 8; ++j)
    cs0[j] = *(const u16x8*)(csum + (size_t)(row0 + 2 * j + r2) * 256 + c32 * 8);
#pragma unroll
  for (int j = 0; j < 8; ++j)
    cs1[j] =
        *(const u16x8*)(csum + (size_t)(row0 + 16 + 2 * j + r2) * 256 + c32 * 8);

  bf16x8 wA[10], wB[10];
  WISS(wA, 0);

  f32x4 acc0[10], acc1[10];
#pragma unroll
  for (int i = 0; i < 10; ++i) {
    acc0[i] = f32x4{0.f, 0.f, 0.f, 0.f};
    acc1[i] = f32x4{0.f, 0.f, 0.f, 0.f};
  }

  // ---- L1 pass 1 (signal half), chunks 0..7 ----
#pragma unroll
  for (int kk = 0; kk < 8; ++kk) {
    if ((kk + 1) & 1) { WISS(wB, kk + 1); } else { WISS(wA, kk + 1); }
    bf16x8 af0 =
        *(const bf16x8*)(act0 + l16 * 512 + ((kk * 64 + lhalf * 16) ^ asw));
    bf16x8 af1 =
        *(const bf16x8*)(act1 + l16 * 512 + ((kk * 64 + lhalf * 16) ^ asw));
    __builtin_amdgcn_s_setprio(1);
    if (kk & 1) {
      MFMA10(acc0, wB, af0); MFMA10(acc1, wB, af1);
    } else {
      MFMA10(acc0, wA, af0); MFMA10(acc1, wA, af1);
    }
    __builtin_amdgcn_s_setprio(0);
  }

  // overwrite act tiles with comp-sum (wave-local)
  asm volatile("" ::: "memory");
#pragma unroll
  for (int j = 0; j < 8; ++j) {
    const int rw = 2 * j + r2;
    *(u16x8*)(act0 + rw * 512 + ((c32 * 16) ^ ((rw & 7) << 4))) = cs0[j];
    *(u16x8*)(act1 + rw * 512 + ((c32 * 16) ^ ((rw & 7) << 4))) = cs1[j];
  }
  asm volatile("" ::: "memory");

  // ---- L1 pass 2 (comp-sum half), chunks 8..15 ----
#pragma unroll
  for (int kk = 8; kk < 16; ++kk) {
    if ((kk + 1) & 1) { WISS(wB, kk + 1); } else { WISS(wA, kk + 1); }
    bf16x8 af0 = *(const bf16x8*)(act0 + l16 * 512 +
                                  (((kk - 8) * 64 + lhalf * 16) ^ asw));
    bf16x8 af1 = *(const bf16x8*)(act1 + l16 * 512 +
                                  (((kk - 8) * 64 + lhalf * 16) ^ asw));
    __builtin_amdgcn_s_setprio(1);
    if (kk & 1) {
      MFMA10(acc0, wB, af0); MFMA10(acc1, wB, af1);
    } else {
      MFMA10(acc0, wA, af0); MFMA10(acc1, wA, af1);
    }
    __builtin_amdgcn_s_setprio(0);
  }

  // bias + relu -> act tiles
  {
    float bv[10];
#pragma unroll
    for (int nt = 0; nt < 10; ++nt) bv[nt] = bias1[nt * 16 + l16];
    asm volatile("" ::: "memory");
#pragma unroll
    for (int nt = 0; nt < 10; ++nt) {
#pragma unroll
      for (int r = 0; r < 4; ++r) {
        const int row = lhalf * 4 + r;
        const int off = (((nt * 16 + l16) * 2) ^ ((row & 7) << 4));
        float v0 = fmaxf(acc0[nt][r] + bv[nt], 0.f);
        float v1 = fmaxf(acc1[nt][r] + bv[nt], 0.f);
        *(unsigned short*)(act0 + row * 512 + off) = f2bf(v0);
        *(unsigned short*)(act1 + row * 512 + off) = f2bf(v1);
      }
    }
    asm volatile("" ::: "memory");
  }

  // ---- hidden layers: chunks 16..20 (W1), 21..25 (W2) ----
  bf16x8 w4A[8], w4B[8];
#pragma unroll
  for (int L = 0; L < 2; ++L) {
    const float* hbias = L ? b2p : b1p;
#pragma unroll
    for (int i = 0; i < 10; ++i) {
      acc0[i] = f32x4{0.f, 0.f, 0.f, 0.f};
      acc1[i] = f32x4{0.f, 0.f, 0.f, 0.f};
    }
#pragma unroll
    for (int qq = 0; qq < 5; ++qq) {
      const int cc = 16 + L * 5 + qq;      // chunk in use (even->wA, odd->wB)
      if (cc < 25) {
        if (cc & 1) { WISS(wA, cc + 1); } else { WISS(wB, cc + 1); }
      } else {
        WISS8L4(w4A, 0);                   // prefetch L4 q=0
      }
      bf16x8 af0 =
          *(const bf16x8*)(act0 + l16 * 512 + ((qq * 64 + lhalf * 16) ^ asw));
      bf16x8 af1 =
          *(const bf16x8*)(act1 + l16 * 512 + ((qq * 64 + lhalf * 16) ^ asw));
      __builtin_amdgcn_s_setprio(1);
      if (cc & 1) {
        MFMA10(acc0, wB, af0); MFMA10(acc1, wB, af1);
      } else {
        MFMA10(acc0, wA, af0); MFMA10(acc1, wA, af1);
      }
      __builtin_amdgcn_s_setprio(0);
    }
    float bv[10];
#pragma unroll
    for (int nt = 0; nt < 10; ++nt) bv[nt] = hbias[nt * 16 + l16];
    asm volatile("" ::: "memory");
#pragma unroll
    for (int nt = 0; nt < 10; ++nt) {
#pragma unroll
      for (int r = 0; r < 4; ++r) {
        const int row = lhalf * 4 + r;
        const int off = (((nt * 16 + l16) * 2) ^ ((row & 7) << 4));
        float v0 = fmaxf(acc0[nt][r] + bv[nt], 0.f);
        float v1 = fmaxf(acc1[nt][r] + bv[nt], 0.f);
        *(unsigned short*)(act0 + row * 512 + off) = f2bf(v0);
        *(unsigned short*)(act1 + row * 512 + off) = f2bf(v1);
      }
    }
    asm volatile("" ::: "memory");
  }

  // ---- layer 4: two N-128 halves h=0,1; q = h*5+kk (even->w4A, odd->w4B) --
#pragma unroll
  for (int h = 0; h < 2; ++h) {
    f32x4 a40[8], a41[8];
#pragma unroll
    for (int i = 0; i < 8; ++i) {
      a40[i] = f32x4{0.f, 0.f, 0.f, 0.f};
      a41[i] = f32x4{0.f, 0.f, 0.f, 0.f};
    }
#pragma unroll
    for (int kk = 0; kk < 5; ++kk) {
      const int q = h * 5 + kk;
      if (q < 9) {
        if (q & 1) { WISS8L4(w4A, q + 1); } else { WISS8L4(w4B, q + 1); }
      }
      bf16x8 af0 =
          *(const bf16x8*)(act0 + l16 * 512 + ((kk * 64 + lhalf * 16) ^ asw));
      bf16x8 af1 =
          *(const bf16x8*)(act1 + l16 * 512 + ((kk * 64 + lhalf * 16) ^ asw));
      __builtin_amdgcn_s_setprio(1);
#pragma unroll
      for (int i = 0; i < 8; ++i) {
        if (q & 1) {
          a40[i] = __builtin_amdgcn_mfma_f32_16x16x32_bf16(af0, w4B[i], a40[i],
                                                           0, 0, 0);
          a41[i] = __builtin_amdgcn_mfma_f32_16x16x32_bf16(af1, w4B[i], a41[i],
                                                           0, 0, 0);
        } else {
          a40[i] = __builtin_amdgcn_mfma_f32_16x16x32_bf16(af0, w4A[i], a40[i],
                                                           0, 0, 0);
          a41[i] = __builtin_amdgcn_mfma_f32_16x16x32_bf16(af1, w4A[i], a41[i],
                                                           0, 0, 0);
        }
      }
      __builtin_amdgcn_s_setprio(0);
    }
    // store this half for both groups
    float bv[8];
#pragma unroll
    for (int i = 0; i < 8; ++i) bv[i] = b3[(h * 8 + i) * 16 + l16];
    float* op0 = out + (size_t)(row0 + lhalf * 4) * 256 + h * 128 + l16;
    float* op1 = out + (size_t)(row0 + 16 + lhalf * 4) * 256 + h * 128 + l16;
#pragma unroll
    for (int i = 0; i < 8; ++i) {
#pragma unroll
      for (int r = 0; r < 4; ++r) {
        op0[(size_t)r * 256 + i * 16] = a40[i][r] + bv[i];
        op1[(size_t)r * 256 + i * 16] = a41[i][r] + bv[i];
      }
    }
  }
}

// ---------------- launcher ----------------
extern "C" void kernel_launch(void* const* d_in, const int* in_sizes, int n_in,
                              void* d_out, int out_size, void* d_ws, size_t ws_size,
                              hipStream_t stream) {
  const float* signal = (const float*)d_in[0];
  const float* comp   = (const float*)d_in[1];
  const float* Wm = (const float*)d_in[2];
  const float* bm = (const float*)d_in[3];
  const float* Wu = (const float*)d_in[4];
  const float* bu = (const float*)d_in[5];
  const float* W0 = (const float*)d_in[6];
  const float* b0 = (const float*)d_in[7];
  const float* W1 = (const float*)d_in[8];
  const float* b1 = (const float*)d_in[9];
  const float* W2 = (const float*)d_in[10];
  const float* b2 = (const float*)d_in[11];
  const float* W3 = (const float*)d_in[12];
  const float* b3 = (const float*)d_in[13];

  char* ws = (char*)d_ws;
  float* Wc    = (float*)(ws + 0);        // 33792 f32 (135168 B)
  float* bias1 = (float*)(ws + 135168);   // 160 f32
  float* b1p   = (float*)(ws + 135808);   // 160 f32
  float* b2p   = (float*)(ws + 136448);   // 160 f32
  // contiguous packed-weight sequence (chunk offsets off P1):
  unsigned short* P1 = (unsigned short*)(ws + 137216);  // 81920 u16 (160KB)
  unsigned short* P2 = (unsigned short*)(ws + 301056);  // 25600 u16 (50KB)
  unsigned short* P3 = (unsigned short*)(ws + 352256);  // 25600 u16 (50KB)
  unsigned short* P4 = (unsigned short*)(ws + 403456);  // 40960 u16 (80KB)
  unsigned short* csum = (unsigned short*)(ws + 485376); // [N,256] bf16 33.5MB

  hipLaunchKernelGGL(kA, dim3(2541), dim3(256), 0, stream,
                     comp, W0, Wu, Wm, bm, bu, b0, b1, b2, W1, W2, W3,
                     Wc, bias1, b1p, b2p, csum, P2, P3, P4);
  hipLaunchKernelGGL(kC, dim3(320), dim3(256), 0, stream, W0, Wc, P1);
  hipLaunchKernelGGL(kD, dim3(512), dim3(256), 65536, stream,
                     signal, csum, P1, bias1, b1p, b2p, b3, (float*)d_out);
}